// Round 1
// baseline (1038.396 us; speedup 1.0000x reference)
//
#include <hip/hip_runtime.h>
#include <hip/hip_bf16.h>
#include <math.h>

#define CC 256
#define HW 16384
#define NPB (CC*HW)   // 4194304 elements per batch sample

typedef __bf16 bf16x8 __attribute__((ext_vector_type(8)));
typedef float  f32x4  __attribute__((ext_vector_type(4)));

struct alignas(8)  bf4_t { __bf16 v[4]; };
struct alignas(16) bf8_t { __bf16 v[8]; };

__device__ __forceinline__ float gelu1(float x){
  return 0.5f * x * (1.0f + erff(x * 0.70710678118654752440f));
}

__device__ __forceinline__ void ld_lds16(const void* g, void* l){
  __builtin_amdgcn_global_load_lds(
      (const __attribute__((address_space(1))) void*)g,
      (__attribute__((address_space(3))) void*)l, 16, 0, 0);
}

// ---------------------------------------------------------------------------
// Shared GEMM core: block tile 128(o) x 128(p), K=256 in 8 slices of 32.
// D[m=o][n=p] = A[o][k] * B[k][p];  A = weights [o][c] row-major bf16,
// B = activations NHWC [p][c] (so B^T rows are contiguous).  Both staged to
// LDS as [row][32k] (64B rows) via global_load_lds width=16.
// Wave w: o-sub = (w&1)*64, p-sub = (w>>1)*64; 4x4 tiles of 16x16x32.
// a-frag: A[m=lane&15][k=q*8+j]; b-frag: B[k=q*8+j][n=lane&15];
// D: row(m)=q*4+r, col(n)=lane&15  (m89/m91-verified layout).
// ---------------------------------------------------------------------------
__device__ __forceinline__ void gemm_core(const __bf16* __restrict__ A0,
                                          const __bf16* __restrict__ B0,
                                          char* smem, f32x4 acc[4][4])
{
  const int t = threadIdx.x, wave = t >> 6, lane = t & 63;
  const int col = lane & 15, q = lane >> 4;
  const int osub = (wave & 1) * 64, psub = (wave >> 1) * 64;
  const int r16 = lane >> 2;      // row within 16-row staging chunk
  const int ch  = lane & 3;       // 16B chunk within 64B row
  char* As = smem;
  char* Bs = smem + 8192;

  for (int kk = 0; kk < 8; kk++){
    __syncthreads();              // prev-iter frag reads done before overwrite
#pragma unroll
    for (int j = 0; j < 2; j++){
      int idx = wave * 2 + j;     // wave-uniform
      ld_lds16(A0 + (size_t)(idx*16 + r16) * CC + kk*32 + ch*8, As + idx*1024);
      ld_lds16(B0 + (size_t)(idx*16 + r16) * CC + kk*32 + ch*8, Bs + idx*1024);
    }
    __syncthreads();              // drains vmcnt (global_load_lds) per wave
    bf16x8 af[4], bfr[4];
#pragma unroll
    for (int mt = 0; mt < 4; mt++)
      af[mt] = *(const bf16x8*)(As + (osub + mt*16 + col)*64 + q*16);
#pragma unroll
    for (int nt = 0; nt < 4; nt++)
      bfr[nt] = *(const bf16x8*)(Bs + (psub + nt*16 + col)*64 + q*16);
#pragma unroll
    for (int mt = 0; mt < 4; mt++)
#pragma unroll
      for (int nt = 0; nt < 4; nt++)
        acc[mt][nt] = __builtin_amdgcn_mfma_f32_16x16x32_bf16(
            af[mt], bfr[nt], acc[mt][nt], 0, 0, 0);
  }
}

// ---------------------------------------------------------------------------
// k_trans: x NCHW fp32 -> xT NHWC bf16, fused per-batch sum/sumsq (GN1 stats)
// 64c x 64p tile through LDS (stride 68 halves: pad kills write conflicts).
// grid (256 p-tiles, 4 c-tiles, 8 b), block 256.
// ---------------------------------------------------------------------------
__global__ __launch_bounds__(256) void k_trans(const float* __restrict__ x,
                                               __bf16* __restrict__ xT,
                                               float* __restrict__ stats1)
{
  __shared__ __bf16 tile[64 * 68];
  __shared__ float red[8];
  const int t = threadIdx.x;
  const int pb = blockIdx.x * 64, cb = blockIdx.y * 64, b = blockIdx.z;
  const float* xb = x + (size_t)b * NPB;
  float s = 0.f, s2 = 0.f;
#pragma unroll
  for (int i = 0; i < 16; i++){
    int e = i * 256 + t;
    int c = e >> 6, p = e & 63;
    float v = xb[(size_t)(cb + c) * HW + pb + p];
    s += v; s2 += v * v;
    tile[p * 68 + c] = (__bf16)v;
  }
  __syncthreads();
  __bf16* xTb = xT + (size_t)b * NPB;
#pragma unroll
  for (int i = 0; i < 4; i++){
    int e = i * 1024 + t * 4;
    int p = e >> 6, c = e & 63;
    bf4_t w;
#pragma unroll
    for (int r = 0; r < 4; r++) w.v[r] = tile[p * 68 + c + r];
    *(bf4_t*)(xTb + (size_t)(pb + p) * CC + cb + c) = w;
  }
  // reduction
  for (int off = 32; off; off >>= 1){
    s  += __shfl_down(s,  off);
    s2 += __shfl_down(s2, off);
  }
  const int wave = t >> 6, lane = t & 63;
  if (lane == 0){ red[wave] = s; red[4 + wave] = s2; }
  __syncthreads();
  if (t == 0){
    atomicAdd(stats1 + b * 2,     red[0] + red[1] + red[2] + red[3]);
    atomicAdd(stats1 + b * 2 + 1, red[4] + red[5] + red[6] + red[7]);
  }
}

// ---------------------------------------------------------------------------
// k_prep: weight folding.  blk0: Wc1 = w1*gn1_w, db1[b][o]; blk1: W4c =
// w4*gn2_w, S1 = w4@gn2_b, S2 = w4@gn2_w; blk2: W5e = w5 @ blockdiag(wg2),
// b5eff = b5 + w5@bg2.  grid 3, block 256 (thread = output channel o).
// ---------------------------------------------------------------------------
__global__ __launch_bounds__(256) void k_prep(
    const float* __restrict__ gn1w, const float* __restrict__ gn1b,
    const float* __restrict__ w1,   const float* __restrict__ b1,
    const float* __restrict__ gn2w, const float* __restrict__ gn2b,
    const float* __restrict__ w4,
    const float* __restrict__ w5,   const float* __restrict__ b5,
    const float* __restrict__ wg2,  const float* __restrict__ bg2,
    const float* __restrict__ stats1,
    __bf16* __restrict__ Wc1, float* __restrict__ db1,
    __bf16* __restrict__ W4c, float* __restrict__ S1, float* __restrict__ S2,
    __bf16* __restrict__ W5e, float* __restrict__ b5eff)
{
  const int o = threadIdx.x;
  if (blockIdx.x == 0){
    float Bg = 0.f, Gw = 0.f;
    for (int c = 0; c < CC; c++){
      float w = w1[o * CC + c];
      Wc1[o * CC + c] = (__bf16)(w * gn1w[c]);
      Bg += w * gn1b[c];
      Gw += w * gn1w[c];
    }
    for (int b = 0; b < 8; b++){
      float ss = stats1[b * 2], sq = stats1[b * 2 + 1];
      float m = ss * (1.f / (float)NPB);
      float r = rsqrtf(sq * (1.f / (float)NPB) - m * m + 1e-5f);
      db1[b * CC + o] = b1[o] + Bg - m * r * Gw;
    }
  } else if (blockIdx.x == 1){
    float a1 = 0.f, a2 = 0.f;
    for (int c = 0; c < CC; c++){
      float w = w4[o * CC + c];
      W4c[o * CC + c] = (__bf16)(w * gn2w[c]);
      a1 += w * gn2b[c];
      a2 += w * gn2w[c];
    }
    S1[o] = a1; S2[o] = a2;
  } else {
    float bb = 0.f;
    for (int c = 0; c < CC; c++){
      int g = c >> 2, j = c & 3;
      float a = 0.f;
#pragma unroll
      for (int i = 0; i < 4; i++)
        a += w5[o * CC + (c & ~3) + i] * wg2[g * 16 + i * 4 + j];
      W5e[o * CC + c] = (__bf16)a;
      bb += w5[o * CC + c] * bg2[c];
    }
    b5eff[o] = b5[o] + bb;
  }
}

// ---------------------------------------------------------------------------
// k_gemm1: y = bf16( r1_b * (Wc1 @ xT) + db1[b][o] )  (GN1 folded conv w1)
// grid (128 p-blocks, 2 o-blocks, 8 b), block 256.
// ---------------------------------------------------------------------------
__global__ __launch_bounds__(256) void k_gemm1(
    const __bf16* __restrict__ Wc1, const __bf16* __restrict__ xT,
    const float* __restrict__ db1, const float* __restrict__ stats1,
    __bf16* __restrict__ y)
{
  __shared__ char smem[16384];
  const int pb = blockIdx.x * 128, ob = blockIdx.y * 128, b = blockIdx.z;
  f32x4 acc[4][4];
#pragma unroll
  for (int i = 0; i < 4; i++)
#pragma unroll
    for (int j = 0; j < 4; j++) acc[i][j] = (f32x4){0.f, 0.f, 0.f, 0.f};
  gemm_core(Wc1 + (size_t)ob * CC, xT + ((size_t)b * HW + pb) * CC, smem, acc);

  const int t = threadIdx.x, wave = t >> 6, lane = t & 63;
  const int col = lane & 15, q = lane >> 4;
  const int osub = (wave & 1) * 64, psub = (wave >> 1) * 64;
  float ss = stats1[b * 2], sq = stats1[b * 2 + 1];
  float m  = ss * (1.f / (float)NPB);
  float r1 = rsqrtf(sq * (1.f / (float)NPB) - m * m + 1e-5f);
#pragma unroll
  for (int mt = 0; mt < 4; mt++){
    int o0 = ob + osub + mt * 16 + q * 4;
    f32x4 d = *(const f32x4*)(db1 + b * CC + o0);
#pragma unroll
    for (int nt = 0; nt < 4; nt++){
      int p = pb + psub + nt * 16 + col;
      bf4_t pk;
#pragma unroll
      for (int r = 0; r < 4; r++) pk.v[r] = (__bf16)(r1 * acc[mt][nt][r] + d[r]);
      *(bf4_t*)(y + ((size_t)b * HW + p) * CC + o0) = pk;
    }
  }
}

// ---------------------------------------------------------------------------
// k_dw: u = gelu(gelu(dw3x3(y) + b2)), pool[b][c] += sum_p u (fp32, atomics).
// NHWC; thread = 8 channels x 1 pixel; block = 8 pixels (one h-row) x 256 ch.
// grid (2048, 8), block 256 (x: 32 ch-octets, y: 8 pixels).
// ---------------------------------------------------------------------------
__global__ __launch_bounds__(256) void k_dw(
    const __bf16* __restrict__ y, const float* __restrict__ w2,
    const float* __restrict__ b2, __bf16* __restrict__ u,
    float* __restrict__ pool)
{
  __shared__ float w2s[2304];
  __shared__ float b2s[256];
  __shared__ float pl[2048];
  const int t = threadIdx.x;
  const int ci = t & 31, py = t >> 5;
  for (int i = t; i < 2304; i += 256) w2s[i] = w2[i];
  b2s[t] = b2[t];
  __syncthreads();

  const int b = blockIdx.y;
  const int p = blockIdx.x * 8 + py;
  const int h = p >> 7, w = p & 127;
  const int c8 = ci * 8;
  const __bf16* yb = y + (size_t)b * NPB;

  float acc[8];
#pragma unroll
  for (int j = 0; j < 8; j++) acc[j] = b2s[c8 + j];
#pragma unroll
  for (int ky = -1; ky <= 1; ky++){
    int hh = h + ky;
    if ((unsigned)hh >= 128u) continue;
#pragma unroll
    for (int kx = -1; kx <= 1; kx++){
      int ww = w + kx;
      if ((unsigned)ww >= 128u) continue;
      bf16x8 v = *(const bf16x8*)(yb + (size_t)(hh * 128 + ww) * CC + c8);
#pragma unroll
      for (int j = 0; j < 8; j++)
        acc[j] += w2s[(c8 + j) * 9 + (ky + 1) * 3 + (kx + 1)] * (float)v[j];
    }
  }
  bf8_t out;
#pragma unroll
  for (int j = 0; j < 8; j++){
    float g = gelu1(gelu1(acc[j]));
    out.v[j] = (__bf16)g;
    pl[py * 256 + c8 + j] = g;
  }
  *(bf8_t*)(u + ((size_t)b * HW + p) * CC + c8) = out;
  __syncthreads();
  float s = 0.f;
#pragma unroll
  for (int k = 0; k < 8; k++) s += pl[k * 256 + t];
  atomicAdd(pool + b * CC + t, s);
}

// ---------------------------------------------------------------------------
// k_att: pooled(u) -> x1-pool (wg1 fold) -> att -> per-batch folded weights
// W3b[b] = w3 @ diag(att) @ blockdiag(wg1), b3eff = b3 + w3@(att*bg1).
// grid 8 (b), block 256 (thread = channel/output).
// ---------------------------------------------------------------------------
__global__ __launch_bounds__(256) void k_att(
    const float* __restrict__ pool, const float* __restrict__ wg1,
    const float* __restrict__ bg1,  const float* __restrict__ wsca,
    const float* __restrict__ bsca, const float* __restrict__ w3,
    const float* __restrict__ b3,
    __bf16* __restrict__ W3b, float* __restrict__ b3eff)
{
  __shared__ float wg1s[1024];
  __shared__ float px1[256];
  __shared__ float attL[256];
  const int t = threadIdx.x, b = blockIdx.x;
  for (int i = t; i < 1024; i += 256) wg1s[i] = wg1[i];
  __syncthreads();
  {  // pooled x1 (after grouped conv + bg1)
    int g = t >> 2, oo = t & 3;
    float a = bg1[t];
#pragma unroll
    for (int j = 0; j < 4; j++)
      a += wg1s[g * 16 + oo * 4 + j] * (pool[b * CC + g * 4 + j] * (1.f / (float)HW));
    px1[t] = a;
  }
  __syncthreads();
  {  // att = w_sca @ px1 + b_sca
    float a = bsca[t];
    const float* wr = wsca + t * CC;
    for (int c = 0; c < CC; c++) a += wr[c] * px1[c];
    attL[t] = a;
  }
  __syncthreads();
  {  // folded per-batch weights
    float bb = b3[t];
    const float* wr = w3 + t * CC;
    for (int c = 0; c < CC; c++){
      int g = c >> 2, j = c & 3;
      float a = 0.f;
#pragma unroll
      for (int i = 0; i < 4; i++)
        a += wr[(c & ~3) + i] * attL[(c & ~3) + i] * wg1s[g * 16 + i * 4 + j];
      W3b[(size_t)b * 65536 + t * CC + c] = (__bf16)a;
      bb += wr[c] * attL[c] * bg1[c];
    }
    b3eff[b * CC + t] = bb;
  }
}

// ---------------------------------------------------------------------------
// k_gemm3: x1res = bf16( (W3b@u + b3eff)*beta + x ), fused GN2 stats atomics.
// ---------------------------------------------------------------------------
__global__ __launch_bounds__(256) void k_gemm3(
    const __bf16* __restrict__ W3b, const __bf16* __restrict__ u,
    const float* __restrict__ b3eff, const float* __restrict__ beta,
    const __bf16* __restrict__ xT,
    __bf16* __restrict__ x1r, float* __restrict__ stats2)
{
  __shared__ char smem[16384];
  const int pb = blockIdx.x * 128, ob = blockIdx.y * 128, b = blockIdx.z;
  f32x4 acc[4][4];
#pragma unroll
  for (int i = 0; i < 4; i++)
#pragma unroll
    for (int j = 0; j < 4; j++) acc[i][j] = (f32x4){0.f, 0.f, 0.f, 0.f};
  gemm_core(W3b + (size_t)b * 65536 + (size_t)ob * CC,
            u + ((size_t)b * HW + pb) * CC, smem, acc);

  const int t = threadIdx.x, wave = t >> 6, lane = t & 63;
  const int col = lane & 15, q = lane >> 4;
  const int osub = (wave & 1) * 64, psub = (wave >> 1) * 64;
  float ls = 0.f, lsq = 0.f;
#pragma unroll
  for (int mt = 0; mt < 4; mt++){
    int o0 = ob + osub + mt * 16 + q * 4;
    f32x4 be = *(const f32x4*)(b3eff + b * CC + o0);
    f32x4 bt = *(const f32x4*)(beta + o0);
#pragma unroll
    for (int nt = 0; nt < 4; nt++){
      int p = pb + psub + nt * 16 + col;
      bf4_t xr = *(const bf4_t*)(xT + ((size_t)b * HW + p) * CC + o0);
      bf4_t pk;
#pragma unroll
      for (int r = 0; r < 4; r++){
        float v = acc[mt][nt][r] + be[r];
        v = v * bt[r] + (float)xr.v[r];
        pk.v[r] = (__bf16)v;
        ls += v; lsq += v * v;
      }
      *(bf4_t*)(x1r + ((size_t)b * HW + p) * CC + o0) = pk;
    }
  }
  for (int off = 32; off; off >>= 1){
    ls  += __shfl_down(ls,  off);
    lsq += __shfl_down(lsq, off);
  }
  __syncthreads();
  float* red = (float*)smem;
  if (lane == 0){ red[wave] = ls; red[4 + wave] = lsq; }
  __syncthreads();
  if (t == 0){
    atomicAdd(stats2 + b * 2,     red[0] + red[1] + red[2] + red[3]);
    atomicAdd(stats2 + b * 2 + 1, red[4] + red[5] + red[6] + red[7]);
  }
}

// ---------------------------------------------------------------------------
// k_gemm4: g = bf16( gelu²( r2_b*(W4c@x1r) + (b4 + S1 - m2*r2*S2) ) )
// ---------------------------------------------------------------------------
__global__ __launch_bounds__(256) void k_gemm4(
    const __bf16* __restrict__ W4c, const __bf16* __restrict__ x1r,
    const float* __restrict__ b4, const float* __restrict__ S1,
    const float* __restrict__ S2, const float* __restrict__ stats2,
    __bf16* __restrict__ g)
{
  __shared__ char smem[16384];
  const int pb = blockIdx.x * 128, ob = blockIdx.y * 128, b = blockIdx.z;
  f32x4 acc[4][4];
#pragma unroll
  for (int i = 0; i < 4; i++)
#pragma unroll
    for (int j = 0; j < 4; j++) acc[i][j] = (f32x4){0.f, 0.f, 0.f, 0.f};
  gemm_core(W4c + (size_t)ob * CC, x1r + ((size_t)b * HW + pb) * CC, smem, acc);

  const int t = threadIdx.x, wave = t >> 6, lane = t & 63;
  const int col = lane & 15, q = lane >> 4;
  const int osub = (wave & 1) * 64, psub = (wave >> 1) * 64;
  float ss = stats2[b * 2], sq = stats2[b * 2 + 1];
  float m2 = ss * (1.f / (float)NPB);
  float r2 = rsqrtf(sq * (1.f / (float)NPB) - m2 * m2 + 1e-5f);
#pragma unroll
  for (int mt = 0; mt < 4; mt++){
    int o0 = ob + osub + mt * 16 + q * 4;
    f32x4 b4v = *(const f32x4*)(b4 + o0);
    f32x4 s1v = *(const f32x4*)(S1 + o0);
    f32x4 s2v = *(const f32x4*)(S2 + o0);
    float db[4];
#pragma unroll
    for (int r = 0; r < 4; r++) db[r] = b4v[r] + s1v[r] - m2 * r2 * s2v[r];
#pragma unroll
    for (int nt = 0; nt < 4; nt++){
      int p = pb + psub + nt * 16 + col;
      bf4_t pk;
#pragma unroll
      for (int r = 0; r < 4; r++){
        float v = r2 * acc[mt][nt][r] + db[r];
        pk.v[r] = (__bf16)gelu1(gelu1(v));
      }
      *(bf4_t*)(g + ((size_t)b * HW + p) * CC + o0) = pk;
    }
  }
}

// ---------------------------------------------------------------------------
// k_gemm5: out(NCHW fp32) = (W5e@g + b5eff)*gamma + x1res
// ---------------------------------------------------------------------------
__global__ __launch_bounds__(256) void k_gemm5(
    const __bf16* __restrict__ W5e, const __bf16* __restrict__ g,
    const float* __restrict__ b5eff, const float* __restrict__ gamma,
    const __bf16* __restrict__ x1r, float* __restrict__ out)
{
  __shared__ char smem[16384];
  const int pb = blockIdx.x * 128, ob = blockIdx.y * 128, b = blockIdx.z;
  f32x4 acc[4][4];
#pragma unroll
  for (int i = 0; i < 4; i++)
#pragma unroll
    for (int j = 0; j < 4; j++) acc[i][j] = (f32x4){0.f, 0.f, 0.f, 0.f};
  gemm_core(W5e + (size_t)ob * CC, g + ((size_t)b * HW + pb) * CC, smem, acc);

  const int t = threadIdx.x, wave = t >> 6, lane = t & 63;
  const int col = lane & 15, q = lane >> 4;
  const int osub = (wave & 1) * 64, psub = (wave >> 1) * 64;
#pragma unroll
  for (int mt = 0; mt < 4; mt++){
    int o0 = ob + osub + mt * 16 + q * 4;
    f32x4 b5v = *(const f32x4*)(b5eff + o0);
    f32x4 gmv = *(const f32x4*)(gamma + o0);
#pragma unroll
    for (int nt = 0; nt < 4; nt++){
      int p = pb + psub + nt * 16 + col;
      bf4_t xr = *(const bf4_t*)(x1r + ((size_t)b * HW + p) * CC + o0);
#pragma unroll
      for (int r = 0; r < 4; r++){
        float v = acc[mt][nt][r] + b5v[r];
        v = v * gmv[r] + (float)xr.v[r];
        out[(size_t)(b * CC + o0 + r) * HW + p] = v;
      }
    }
  }
}

// ---------------------------------------------------------------------------
extern "C" void kernel_launch(void* const* d_in, const int* in_sizes, int n_in,
                              void* d_out, int out_size, void* d_ws, size_t ws_size,
                              hipStream_t stream)
{
  (void)in_sizes; (void)n_in; (void)out_size; (void)ws_size;
  const float* x     = (const float*)d_in[0];
  const float* gn1w  = (const float*)d_in[1];
  const float* gn1b  = (const float*)d_in[2];
  const float* w1    = (const float*)d_in[3];
  const float* b1    = (const float*)d_in[4];
  const float* w2    = (const float*)d_in[5];
  const float* b2    = (const float*)d_in[6];
  const float* wg1   = (const float*)d_in[7];
  const float* bg1   = (const float*)d_in[8];
  const float* wsca  = (const float*)d_in[9];
  const float* bsca  = (const float*)d_in[10];
  const float* w3    = (const float*)d_in[11];
  const float* b3    = (const float*)d_in[12];
  const float* gn2w  = (const float*)d_in[13];
  const float* gn2b  = (const float*)d_in[14];
  const float* w4    = (const float*)d_in[15];
  const float* b4    = (const float*)d_in[16];
  const float* wg2   = (const float*)d_in[17];
  const float* bg2   = (const float*)d_in[18];
  const float* w5    = (const float*)d_in[19];
  const float* b5    = (const float*)d_in[20];
  const float* beta  = (const float*)d_in[21];
  const float* gamma = (const float*)d_in[22];

  char* ws = (char*)d_ws;
  __bf16* xT  = (__bf16*)(ws + 0);            // 64 MB  NHWC bf16 of x
  __bf16* y   = (__bf16*)(ws + 67108864);     // 64 MB  conv1 out; reused as g
  __bf16* u   = (__bf16*)(ws + 134217728);    // 64 MB  gelu²(dwconv) out
  __bf16* x1r = (__bf16*)(ws + 201326592);    // 64 MB  x1 residual carrier
  char*   sm  = ws + 268435456;
  float* stats1 = (float*)(sm);           // 16 f32
  float* stats2 = (float*)(sm + 64);      // 16 f32
  float* pool   = (float*)(sm + 128);     // 2048 f32
  float* db1    = (float*)(sm + 8320);    // 2048 f32
  float* S1     = (float*)(sm + 16512);   // 256 f32
  float* S2     = (float*)(sm + 17536);   // 256 f32
  float* b3eff  = (float*)(sm + 18560);   // 2048 f32
  float* b5eff  = (float*)(sm + 26752);   // 256 f32
  __bf16* Wc1   = (__bf16*)(sm + 32768);  // 128 KB
  __bf16* W4c   = (__bf16*)(sm + 163840); // 128 KB
  __bf16* W5e   = (__bf16*)(sm + 294912); // 128 KB
  __bf16* W3b   = (__bf16*)(sm + 425984); // 1 MB (8 batches)

  hipMemsetAsync(sm, 0, 8320, stream);  // zero stats1, stats2, pool

  k_trans<<<dim3(256, 4, 8), 256, 0, stream>>>(x, xT, stats1);
  k_prep <<<3, 256, 0, stream>>>(gn1w, gn1b, w1, b1, gn2w, gn2b, w4,
                                 w5, b5, wg2, bg2, stats1,
                                 Wc1, db1, W4c, S1, S2, W5e, b5eff);
  k_gemm1<<<dim3(128, 2, 8), 256, 0, stream>>>(Wc1, xT, db1, stats1, y);
  k_dw   <<<dim3(2048, 8), 256, 0, stream>>>(y, w2, b2, u, pool);
  k_att  <<<8, 256, 0, stream>>>(pool, wg1, bg1, wsca, bsca, w3, b3, W3b, b3eff);
  k_gemm3<<<dim3(128, 2, 8), 256, 0, stream>>>(W3b, u, b3eff, beta, xT, x1r, stats2);
  k_gemm4<<<dim3(128, 2, 8), 256, 0, stream>>>(W4c, x1r, b4, S1, S2, stats2, y);
  k_gemm5<<<dim3(128, 2, 8), 256, 0, stream>>>(W5e, y, b5eff, gamma, x1r,
                                               (float*)d_out);
}

// Round 2
// 831.883 us; speedup vs baseline: 1.2482x; 1.2482x over previous
//
#include <hip/hip_runtime.h>
#include <hip/hip_bf16.h>
#include <math.h>

#define CC 256
#define HW 16384
#define NPB (CC*HW)   // 4194304 elements per batch sample

typedef __bf16 bf16x8 __attribute__((ext_vector_type(8)));
typedef float  f32x4  __attribute__((ext_vector_type(4)));

struct alignas(8)  bf4_t { __bf16 v[4]; };
struct alignas(16) bf8_t { __bf16 v[8]; };

__device__ __forceinline__ float gelu1(float x){
  return 0.5f * x * (1.0f + erff(x * 0.70710678118654752440f));
}

__device__ __forceinline__ void ld_lds16(const void* g, void* l){
  __builtin_amdgcn_global_load_lds(
      (const __attribute__((address_space(1))) void*)g,
      (__attribute__((address_space(3))) void*)l, 16, 0, 0);
}

// ---------------------------------------------------------------------------
// Shared GEMM core: block tile 128(o) x 128(p), K=256 in 8 slices of 32.
// (unchanged from round 1 — verified correct; counters next round)
// ---------------------------------------------------------------------------
__device__ __forceinline__ void gemm_core(const __bf16* __restrict__ A0,
                                          const __bf16* __restrict__ B0,
                                          char* smem, f32x4 acc[4][4])
{
  const int t = threadIdx.x, wave = t >> 6, lane = t & 63;
  const int col = lane & 15, q = lane >> 4;
  const int osub = (wave & 1) * 64, psub = (wave >> 1) * 64;
  const int r16 = lane >> 2;      // row within 16-row staging chunk
  const int ch  = lane & 3;       // 16B chunk within 64B row
  char* As = smem;
  char* Bs = smem + 8192;

  for (int kk = 0; kk < 8; kk++){
    __syncthreads();
#pragma unroll
    for (int j = 0; j < 2; j++){
      int idx = wave * 2 + j;     // wave-uniform
      ld_lds16(A0 + (size_t)(idx*16 + r16) * CC + kk*32 + ch*8, As + idx*1024);
      ld_lds16(B0 + (size_t)(idx*16 + r16) * CC + kk*32 + ch*8, Bs + idx*1024);
    }
    __syncthreads();
    bf16x8 af[4], bfr[4];
#pragma unroll
    for (int mt = 0; mt < 4; mt++)
      af[mt] = *(const bf16x8*)(As + (osub + mt*16 + col)*64 + q*16);
#pragma unroll
    for (int nt = 0; nt < 4; nt++)
      bfr[nt] = *(const bf16x8*)(Bs + (psub + nt*16 + col)*64 + q*16);
#pragma unroll
    for (int mt = 0; mt < 4; mt++)
#pragma unroll
      for (int nt = 0; nt < 4; nt++)
        acc[mt][nt] = __builtin_amdgcn_mfma_f32_16x16x32_bf16(
            af[mt], bfr[nt], acc[mt][nt], 0, 0, 0);
  }
}

// ---------------------------------------------------------------------------
// k_trans v2: x NCHW fp32 -> xT NHWC bf16 + fused GN1 stats.
// Tile 64 p x 128 c.  Output row segments = 128c*2B = 256 B (full HBM
// granule -> no write amplification); 16-B bf16x8 stores; loads batched
// 16-deep in registers.  LDS pitch 272 B (16-B aligned for ds_read_b128).
// grid (256 p-tiles, 2 c-tiles, 8 b), block 256.
// ---------------------------------------------------------------------------
__global__ __launch_bounds__(256) void k_trans(const float* __restrict__ x,
                                               __bf16* __restrict__ xT,
                                               float* __restrict__ stats1)
{
  __shared__ __bf16 tile[64 * 136];   // 64 p rows, pitch 136 bf16 = 272 B
  __shared__ float red[8];
  const int t = threadIdx.x;
  const int pb = blockIdx.x * 64, cb = blockIdx.y * 128, b = blockIdx.z;
  const float* xb = x + (size_t)b * NPB;
  const int p = t & 63, cq = t >> 6;            // cq in 0..3
  float s = 0.f, s2 = 0.f;
#pragma unroll
  for (int h = 0; h < 2; h++){
    float v[16];
#pragma unroll
    for (int u = 0; u < 16; u++){
      int c = cq * 32 + h * 16 + u;
      v[u] = xb[(size_t)(cb + c) * HW + pb + p];   // 256B/row coalesced
    }
#pragma unroll
    for (int g = 0; g < 4; g++){
      bf4_t pk;
#pragma unroll
      for (int j = 0; j < 4; j++){
        float vv = v[g * 4 + j];
        s += vv; s2 += vv * vv;
        pk.v[j] = (__bf16)vv;
      }
      *(bf4_t*)&tile[p * 136 + cq * 32 + h * 16 + g * 4] = pk;
    }
  }
  __syncthreads();
  __bf16* xTb = xT + (size_t)b * NPB;
#pragma unroll
  for (int si = 0; si < 4; si++){
    int pp = si * 16 + (t >> 4);
    int c0 = (t & 15) * 8;
    *(bf8_t*)(xTb + (size_t)(pb + pp) * CC + cb + c0) =
        *(bf8_t*)&tile[pp * 136 + c0];           // 16 lanes -> 256 B/row
  }
  for (int off = 32; off; off >>= 1){
    s  += __shfl_down(s,  off);
    s2 += __shfl_down(s2, off);
  }
  const int wave = t >> 6, lane = t & 63;
  if (lane == 0){ red[wave] = s; red[4 + wave] = s2; }
  __syncthreads();
  if (t == 0){
    atomicAdd(stats1 + b * 2,     red[0] + red[1] + red[2] + red[3]);
    atomicAdd(stats1 + b * 2 + 1, red[4] + red[5] + red[6] + red[7]);
  }
}

// ---------------------------------------------------------------------------
// k_prep v2: one block per output row o.  grid 768 = 3 matrices x 256 o.
// which==0: Wc1 = w1*gn1w (+db1);  1: W4c = w4*gn2w (+S1,S2);
// 2: W5e = w5 @ blockdiag(wg2) (+b5eff).  Thread = input channel c.
// ---------------------------------------------------------------------------
__global__ __launch_bounds__(256) void k_prep(
    const float* __restrict__ gn1w, const float* __restrict__ gn1b,
    const float* __restrict__ w1,   const float* __restrict__ b1,
    const float* __restrict__ gn2w, const float* __restrict__ gn2b,
    const float* __restrict__ w4,
    const float* __restrict__ w5,   const float* __restrict__ b5,
    const float* __restrict__ wg2,  const float* __restrict__ bg2,
    const float* __restrict__ stats1,
    __bf16* __restrict__ Wc1, float* __restrict__ db1,
    __bf16* __restrict__ W4c, float* __restrict__ S1, float* __restrict__ S2,
    __bf16* __restrict__ W5e, float* __restrict__ b5eff)
{
  __shared__ float redA[4], redB[4];
  const int c = threadIdx.x;
  const int which = blockIdx.x >> 8, o = blockIdx.x & 255;
  float a = 0.f, g = 0.f;
  if (which == 0){
    float w = w1[o * CC + c];
    Wc1[o * CC + c] = (__bf16)(w * gn1w[c]);
    a = w * gn1b[c];
    g = w * gn1w[c];
  } else if (which == 1){
    float w = w4[o * CC + c];
    W4c[o * CC + c] = (__bf16)(w * gn2w[c]);
    a = w * gn2b[c];
    g = w * gn2w[c];
  } else {
    int gr = c >> 2, j = c & 3, base = c & ~3;
    float acc = 0.f;
#pragma unroll
    for (int i = 0; i < 4; i++)
      acc += w5[o * CC + base + i] * wg2[gr * 16 + i * 4 + j];
    W5e[o * CC + c] = (__bf16)acc;
    a = w5[o * CC + c] * bg2[c];
  }
  for (int off = 32; off; off >>= 1){
    a += __shfl_down(a, off);
    g += __shfl_down(g, off);
  }
  const int wave = c >> 6, lane = c & 63;
  if (lane == 0){ redA[wave] = a; redB[wave] = g; }
  __syncthreads();
  if (c == 0){
    float A = redA[0] + redA[1] + redA[2] + redA[3];
    float G = redB[0] + redB[1] + redB[2] + redB[3];
    if (which == 0){
      for (int b = 0; b < 8; b++){
        float ss = stats1[b * 2], sq = stats1[b * 2 + 1];
        float m = ss * (1.f / (float)NPB);
        float r = rsqrtf(sq * (1.f / (float)NPB) - m * m + 1e-5f);
        db1[b * CC + o] = b1[o] + A - m * r * G;
      }
    } else if (which == 1){
      S1[o] = A; S2[o] = G;
    } else {
      b5eff[o] = b5[o] + A;
    }
  }
}

// ---------------------------------------------------------------------------
// k_gemm1: y = bf16( r1_b * (Wc1 @ xT) + db1[b][o] )
// ---------------------------------------------------------------------------
__global__ __launch_bounds__(256) void k_gemm1(
    const __bf16* __restrict__ Wc1, const __bf16* __restrict__ xT,
    const float* __restrict__ db1, const float* __restrict__ stats1,
    __bf16* __restrict__ y)
{
  __shared__ char smem[16384];
  const int pb = blockIdx.x * 128, ob = blockIdx.y * 128, b = blockIdx.z;
  f32x4 acc[4][4];
#pragma unroll
  for (int i = 0; i < 4; i++)
#pragma unroll
    for (int j = 0; j < 4; j++) acc[i][j] = (f32x4){0.f, 0.f, 0.f, 0.f};
  gemm_core(Wc1 + (size_t)ob * CC, xT + ((size_t)b * HW + pb) * CC, smem, acc);

  const int t = threadIdx.x, wave = t >> 6, lane = t & 63;
  const int col = lane & 15, q = lane >> 4;
  const int osub = (wave & 1) * 64, psub = (wave >> 1) * 64;
  float ss = stats1[b * 2], sq = stats1[b * 2 + 1];
  float m  = ss * (1.f / (float)NPB);
  float r1 = rsqrtf(sq * (1.f / (float)NPB) - m * m + 1e-5f);
#pragma unroll
  for (int mt = 0; mt < 4; mt++){
    int o0 = ob + osub + mt * 16 + q * 4;
    f32x4 d = *(const f32x4*)(db1 + b * CC + o0);
#pragma unroll
    for (int nt = 0; nt < 4; nt++){
      int p = pb + psub + nt * 16 + col;
      bf4_t pk;
#pragma unroll
      for (int r = 0; r < 4; r++) pk.v[r] = (__bf16)(r1 * acc[mt][nt][r] + d[r]);
      *(bf4_t*)(y + ((size_t)b * HW + p) * CC + o0) = pk;
    }
  }
}

// ---------------------------------------------------------------------------
// k_dw: u = gelu(gelu(dw3x3(y) + b2)), pool[b][c] += sum_p u.
// ---------------------------------------------------------------------------
__global__ __launch_bounds__(256) void k_dw(
    const __bf16* __restrict__ y, const float* __restrict__ w2,
    const float* __restrict__ b2, __bf16* __restrict__ u,
    float* __restrict__ pool)
{
  __shared__ float w2s[2304];
  __shared__ float b2s[256];
  __shared__ float pl[2048];
  const int t = threadIdx.x;
  const int ci = t & 31, py = t >> 5;
  for (int i = t; i < 2304; i += 256) w2s[i] = w2[i];
  b2s[t] = b2[t];
  __syncthreads();

  const int b = blockIdx.y;
  const int p = blockIdx.x * 8 + py;
  const int h = p >> 7, w = p & 127;
  const int c8 = ci * 8;
  const __bf16* yb = y + (size_t)b * NPB;

  float acc[8];
#pragma unroll
  for (int j = 0; j < 8; j++) acc[j] = b2s[c8 + j];
#pragma unroll
  for (int ky = -1; ky <= 1; ky++){
    int hh = h + ky;
    if ((unsigned)hh >= 128u) continue;
#pragma unroll
    for (int kx = -1; kx <= 1; kx++){
      int ww = w + kx;
      if ((unsigned)ww >= 128u) continue;
      bf16x8 v = *(const bf16x8*)(yb + (size_t)(hh * 128 + ww) * CC + c8);
#pragma unroll
      for (int j = 0; j < 8; j++)
        acc[j] += w2s[(c8 + j) * 9 + (ky + 1) * 3 + (kx + 1)] * (float)v[j];
    }
  }
  bf8_t out;
#pragma unroll
  for (int j = 0; j < 8; j++){
    float g = gelu1(gelu1(acc[j]));
    out.v[j] = (__bf16)g;
    pl[py * 256 + c8 + j] = g;
  }
  *(bf8_t*)(u + ((size_t)b * HW + p) * CC + c8) = out;
  __syncthreads();
  float s = 0.f;
#pragma unroll
  for (int k = 0; k < 8; k++) s += pl[k * 256 + t];
  atomicAdd(pool + b * CC + t, s);
}

// ---------------------------------------------------------------------------
// k_att v2 (small): pooled -> px1 -> att; writes attB[b][256] and b3eff.
// grid 8 (b), block 256.
// ---------------------------------------------------------------------------
__global__ __launch_bounds__(256) void k_att(
    const float* __restrict__ pool, const float* __restrict__ wg1,
    const float* __restrict__ bg1,  const float* __restrict__ wsca,
    const float* __restrict__ bsca, const float* __restrict__ w3,
    const float* __restrict__ b3,
    float* __restrict__ attB, float* __restrict__ b3eff)
{
  __shared__ float wg1s[1024];
  __shared__ float px1[256];
  __shared__ float attL[256];
  const int t = threadIdx.x, b = blockIdx.x;
  for (int i = t; i < 1024; i += 256) wg1s[i] = wg1[i];
  __syncthreads();
  {
    int g = t >> 2, oo = t & 3;
    float a = bg1[t];
#pragma unroll
    for (int j = 0; j < 4; j++)
      a += wg1s[g * 16 + oo * 4 + j] * (pool[b * CC + g * 4 + j] * (1.f / (float)HW));
    px1[t] = a;
  }
  __syncthreads();
  {
    float a = bsca[t];
    const float* wr = wsca + t * CC;
    for (int c = 0; c < CC; c++) a += wr[c] * px1[c];
    attL[t] = a;
    attB[b * CC + t] = a;
  }
  __syncthreads();
  {
    float bb = b3[t];
    const float* wr = w3 + t * CC;
    for (int c = 0; c < CC; c++) bb += wr[c] * attL[c] * bg1[c];
    b3eff[b * CC + t] = bb;
  }
}

// ---------------------------------------------------------------------------
// k_attW: W3b[b] = w3 @ diag(att) @ blockdiag(wg1), parallel fold.
// grid (16 o-groups, 8 b), block 256; w3 rows staged in LDS.
// ---------------------------------------------------------------------------
__global__ __launch_bounds__(256) void k_attW(
    const float* __restrict__ attB, const float* __restrict__ w3,
    const float* __restrict__ wg1, __bf16* __restrict__ W3b)
{
  __shared__ float w3s[4096];
  __shared__ float wg1s[1024];
  __shared__ float attS[256];
  const int t = threadIdx.x;
  const int og = blockIdx.x, b = blockIdx.y;
  const int o0 = og * 16;
  for (int i = t; i < 4096; i += 256) w3s[i] = w3[o0 * 256 + i];
  for (int i = t; i < 1024; i += 256) wg1s[i] = wg1[i];
  attS[t] = attB[b * 256 + t];
  __syncthreads();
  const int ol = t >> 4, ci = t & 15;
  __bf16* out = W3b + (size_t)b * 65536 + (size_t)(o0 + ol) * 256;
#pragma unroll
  for (int cc = 0; cc < 16; cc++){
    int c = cc * 16 + ci;
    int g = c >> 2, j = c & 3, base = c & ~3;
    float a = 0.f;
#pragma unroll
    for (int i = 0; i < 4; i++)
      a += w3s[ol * 256 + base + i] * attS[base + i] * wg1s[g * 16 + i * 4 + j];
    out[c] = (__bf16)a;
  }
}

// ---------------------------------------------------------------------------
// k_gemm3: x1res = bf16( (W3b@u + b3eff)*beta + x ), fused GN2 stats.
// ---------------------------------------------------------------------------
__global__ __launch_bounds__(256) void k_gemm3(
    const __bf16* __restrict__ W3b, const __bf16* __restrict__ u,
    const float* __restrict__ b3eff, const float* __restrict__ beta,
    const __bf16* __restrict__ xT,
    __bf16* __restrict__ x1r, float* __restrict__ stats2)
{
  __shared__ char smem[16384];
  const int pb = blockIdx.x * 128, ob = blockIdx.y * 128, b = blockIdx.z;
  f32x4 acc[4][4];
#pragma unroll
  for (int i = 0; i < 4; i++)
#pragma unroll
    for (int j = 0; j < 4; j++) acc[i][j] = (f32x4){0.f, 0.f, 0.f, 0.f};
  gemm_core(W3b + (size_t)b * 65536 + (size_t)ob * CC,
            u + ((size_t)b * HW + pb) * CC, smem, acc);

  const int t = threadIdx.x, wave = t >> 6, lane = t & 63;
  const int col = lane & 15, q = lane >> 4;
  const int osub = (wave & 1) * 64, psub = (wave >> 1) * 64;
  float ls = 0.f, lsq = 0.f;
#pragma unroll
  for (int mt = 0; mt < 4; mt++){
    int o0 = ob + osub + mt * 16 + q * 4;
    f32x4 be = *(const f32x4*)(b3eff + b * CC + o0);
    f32x4 bt = *(const f32x4*)(beta + o0);
#pragma unroll
    for (int nt = 0; nt < 4; nt++){
      int p = pb + psub + nt * 16 + col;
      bf4_t xr = *(const bf4_t*)(xT + ((size_t)b * HW + p) * CC + o0);
      bf4_t pk;
#pragma unroll
      for (int r = 0; r < 4; r++){
        float v = acc[mt][nt][r] + be[r];
        v = v * bt[r] + (float)xr.v[r];
        pk.v[r] = (__bf16)v;
        ls += v; lsq += v * v;
      }
      *(bf4_t*)(x1r + ((size_t)b * HW + p) * CC + o0) = pk;
    }
  }
  for (int off = 32; off; off >>= 1){
    ls  += __shfl_down(ls,  off);
    lsq += __shfl_down(lsq, off);
  }
  __syncthreads();
  float* red = (float*)smem;
  if (lane == 0){ red[wave] = ls; red[4 + wave] = lsq; }
  __syncthreads();
  if (t == 0){
    atomicAdd(stats2 + b * 2,     red[0] + red[1] + red[2] + red[3]);
    atomicAdd(stats2 + b * 2 + 1, red[4] + red[5] + red[6] + red[7]);
  }
}

// ---------------------------------------------------------------------------
// k_gemm4: g = bf16( gelu²( r2_b*(W4c@x1r) + (b4 + S1 - m2*r2*S2) ) )
// ---------------------------------------------------------------------------
__global__ __launch_bounds__(256) void k_gemm4(
    const __bf16* __restrict__ W4c, const __bf16* __restrict__ x1r,
    const float* __restrict__ b4, const float* __restrict__ S1,
    const float* __restrict__ S2, const float* __restrict__ stats2,
    __bf16* __restrict__ g)
{
  __shared__ char smem[16384];
  const int pb = blockIdx.x * 128, ob = blockIdx.y * 128, b = blockIdx.z;
  f32x4 acc[4][4];
#pragma unroll
  for (int i = 0; i < 4; i++)
#pragma unroll
    for (int j = 0; j < 4; j++) acc[i][j] = (f32x4){0.f, 0.f, 0.f, 0.f};
  gemm_core(W4c + (size_t)ob * CC, x1r + ((size_t)b * HW + pb) * CC, smem, acc);

  const int t = threadIdx.x, wave = t >> 6, lane = t & 63;
  const int col = lane & 15, q = lane >> 4;
  const int osub = (wave & 1) * 64, psub = (wave >> 1) * 64;
  float ss = stats2[b * 2], sq = stats2[b * 2 + 1];
  float m2 = ss * (1.f / (float)NPB);
  float r2 = rsqrtf(sq * (1.f / (float)NPB) - m2 * m2 + 1e-5f);
#pragma unroll
  for (int mt = 0; mt < 4; mt++){
    int o0 = ob + osub + mt * 16 + q * 4;
    f32x4 b4v = *(const f32x4*)(b4 + o0);
    f32x4 s1v = *(const f32x4*)(S1 + o0);
    f32x4 s2v = *(const f32x4*)(S2 + o0);
    float db[4];
#pragma unroll
    for (int r = 0; r < 4; r++) db[r] = b4v[r] + s1v[r] - m2 * r2 * s2v[r];
#pragma unroll
    for (int nt = 0; nt < 4; nt++){
      int p = pb + psub + nt * 16 + col;
      bf4_t pk;
#pragma unroll
      for (int r = 0; r < 4; r++){
        float v = r2 * acc[mt][nt][r] + db[r];
        pk.v[r] = (__bf16)gelu1(gelu1(v));
      }
      *(bf4_t*)(g + ((size_t)b * HW + p) * CC + o0) = pk;
    }
  }
}

// ---------------------------------------------------------------------------
// k_gemm5: out(NCHW fp32) = (W5e@g + b5eff)*gamma + x1res
// ---------------------------------------------------------------------------
__global__ __launch_bounds__(256) void k_gemm5(
    const __bf16* __restrict__ W5e, const __bf16* __restrict__ g,
    const float* __restrict__ b5eff, const float* __restrict__ gamma,
    const __bf16* __restrict__ x1r, float* __restrict__ out)
{
  __shared__ char smem[16384];
  const int pb = blockIdx.x * 128, ob = blockIdx.y * 128, b = blockIdx.z;
  f32x4 acc[4][4];
#pragma unroll
  for (int i = 0; i < 4; i++)
#pragma unroll
    for (int j = 0; j < 4; j++) acc[i][j] = (f32x4){0.f, 0.f, 0.f, 0.f};
  gemm_core(W5e + (size_t)ob * CC, g + ((size_t)b * HW + pb) * CC, smem, acc);

  const int t = threadIdx.x, wave = t >> 6, lane = t & 63;
  const int col = lane & 15, q = lane >> 4;
  const int osub = (wave & 1) * 64, psub = (wave >> 1) * 64;
#pragma unroll
  for (int mt = 0; mt < 4; mt++){
    int o0 = ob + osub + mt * 16 + q * 4;
    f32x4 b5v = *(const f32x4*)(b5eff + o0);
    f32x4 gmv = *(const f32x4*)(gamma + o0);
#pragma unroll
    for (int nt = 0; nt < 4; nt++){
      int p = pb + psub + nt * 16 + col;
      bf4_t xr = *(const bf4_t*)(x1r + ((size_t)b * HW + p) * CC + o0);
#pragma unroll
      for (int r = 0; r < 4; r++){
        float v = acc[mt][nt][r] + b5v[r];
        v = v * gmv[r] + (float)xr.v[r];
        out[(size_t)(b * CC + o0 + r) * HW + p] = v;
      }
    }
  }
}

// ---------------------------------------------------------------------------
extern "C" void kernel_launch(void* const* d_in, const int* in_sizes, int n_in,
                              void* d_out, int out_size, void* d_ws, size_t ws_size,
                              hipStream_t stream)
{
  (void)in_sizes; (void)n_in; (void)out_size; (void)ws_size;
  const float* x     = (const float*)d_in[0];
  const float* gn1w  = (const float*)d_in[1];
  const float* gn1b  = (const float*)d_in[2];
  const float* w1    = (const float*)d_in[3];
  const float* b1    = (const float*)d_in[4];
  const float* w2    = (const float*)d_in[5];
  const float* b2    = (const float*)d_in[6];
  const float* wg1   = (const float*)d_in[7];
  const float* bg1   = (const float*)d_in[8];
  const float* wsca  = (const float*)d_in[9];
  const float* bsca  = (const float*)d_in[10];
  const float* w3    = (const float*)d_in[11];
  const float* b3    = (const float*)d_in[12];
  const float* gn2w  = (const float*)d_in[13];
  const float* gn2b  = (const float*)d_in[14];
  const float* w4    = (const float*)d_in[15];
  const float* b4    = (const float*)d_in[16];
  const float* wg2   = (const float*)d_in[17];
  const float* bg2   = (const float*)d_in[18];
  const float* w5    = (const float*)d_in[19];
  const float* b5    = (const float*)d_in[20];
  const float* beta  = (const float*)d_in[21];
  const float* gamma = (const float*)d_in[22];

  char* ws = (char*)d_ws;
  __bf16* xT  = (__bf16*)(ws + 0);            // 64 MB  NHWC bf16 of x
  __bf16* y   = (__bf16*)(ws + 67108864);     // 64 MB  conv1 out; reused as g
  __bf16* u   = (__bf16*)(ws + 134217728);    // 64 MB  gelu²(dwconv) out
  __bf16* x1r = (__bf16*)(ws + 201326592);    // 64 MB  x1 residual carrier
  char*   sm  = ws + 268435456;
  float* stats1 = (float*)(sm);            // 16 f32
  float* stats2 = (float*)(sm + 64);       // 16 f32
  float* pool   = (float*)(sm + 128);      // 2048 f32 (ends 8320)
  float* db1    = (float*)(sm + 8320);     // 2048 f32
  float* S1     = (float*)(sm + 16512);    // 256 f32
  float* S2     = (float*)(sm + 17536);    // 256 f32
  float* b3eff  = (float*)(sm + 18560);    // 2048 f32
  float* b5eff  = (float*)(sm + 26752);    // 256 f32
  float* attB   = (float*)(sm + 27776);    // 2048 f32
  __bf16* Wc1   = (__bf16*)(sm + 36864);   // 128 KB
  __bf16* W4c   = (__bf16*)(sm + 167936);  // 128 KB
  __bf16* W5e   = (__bf16*)(sm + 299008);  // 128 KB
  __bf16* W3b   = (__bf16*)(sm + 430080);  // 1 MB (8 batches)

  hipMemsetAsync(sm, 0, 8320, stream);  // zero stats1, stats2, pool

  k_trans<<<dim3(256, 2, 8), 256, 0, stream>>>(x, xT, stats1);
  k_prep <<<768, 256, 0, stream>>>(gn1w, gn1b, w1, b1, gn2w, gn2b, w4,
                                   w5, b5, wg2, bg2, stats1,
                                   Wc1, db1, W4c, S1, S2, W5e, b5eff);
  k_gemm1<<<dim3(128, 2, 8), 256, 0, stream>>>(Wc1, xT, db1, stats1, y);
  k_dw   <<<dim3(2048, 8), 256, 0, stream>>>(y, w2, b2, u, pool);
  k_att  <<<8, 256, 0, stream>>>(pool, wg1, bg1, wsca, bsca, w3, b3, attB, b3eff);
  k_attW <<<dim3(16, 8), 256, 0, stream>>>(attB, w3, wg1, W3b);
  k_gemm3<<<dim3(128, 2, 8), 256, 0, stream>>>(W3b, u, b3eff, beta, xT, x1r, stats2);
  k_gemm4<<<dim3(128, 2, 8), 256, 0, stream>>>(W4c, x1r, b4, S1, S2, stats2, y);
  k_gemm5<<<dim3(128, 2, 8), 256, 0, stream>>>(W5e, y, b5eff, gamma, x1r,
                                               (float*)d_out);
}

// Round 3
// 720.947 us; speedup vs baseline: 1.4403x; 1.1539x over previous
//
#include <hip/hip_runtime.h>
#include <hip/hip_bf16.h>
#include <math.h>

#define CC 256
#define HW 16384
#define NPB (CC*HW)   // 4194304 elements per batch sample

typedef __bf16 bf16x8 __attribute__((ext_vector_type(8)));
typedef float  f32x4  __attribute__((ext_vector_type(4)));

struct alignas(8)  bf4_t { __bf16 v[4]; };
struct alignas(16) bf8_t { __bf16 v[8]; };

__device__ __forceinline__ float gelu1(float x){
  return 0.5f * x * (1.0f + erff(x * 0.70710678118654752440f));
}

__device__ __forceinline__ void ld_lds16(const void* g, void* l){
  __builtin_amdgcn_global_load_lds(
      (const __attribute__((address_space(1))) void*)g,
      (__attribute__((address_space(3))) void*)l, 16, 0, 0);
}

// ---------------------------------------------------------------------------
// Shared GEMM core: block tile 128(o) x 128(p), K=256 in 8 slices of 32.
// ---------------------------------------------------------------------------
__device__ __forceinline__ void gemm_core(const __bf16* __restrict__ A0,
                                          const __bf16* __restrict__ B0,
                                          char* smem, f32x4 acc[4][4])
{
  const int t = threadIdx.x, wave = t >> 6, lane = t & 63;
  const int col = lane & 15, q = lane >> 4;
  const int osub = (wave & 1) * 64, psub = (wave >> 1) * 64;
  const int r16 = lane >> 2;      // row within 16-row staging chunk
  const int ch  = lane & 3;       // 16B chunk within 64B row
  char* As = smem;
  char* Bs = smem + 8192;

  for (int kk = 0; kk < 8; kk++){
    __syncthreads();
#pragma unroll
    for (int j = 0; j < 2; j++){
      int idx = wave * 2 + j;     // wave-uniform
      ld_lds16(A0 + (size_t)(idx*16 + r16) * CC + kk*32 + ch*8, As + idx*1024);
      ld_lds16(B0 + (size_t)(idx*16 + r16) * CC + kk*32 + ch*8, Bs + idx*1024);
    }
    __syncthreads();
    bf16x8 af[4], bfr[4];
#pragma unroll
    for (int mt = 0; mt < 4; mt++)
      af[mt] = *(const bf16x8*)(As + (osub + mt*16 + col)*64 + q*16);
#pragma unroll
    for (int nt = 0; nt < 4; nt++)
      bfr[nt] = *(const bf16x8*)(Bs + (psub + nt*16 + col)*64 + q*16);
#pragma unroll
    for (int mt = 0; mt < 4; mt++)
#pragma unroll
      for (int nt = 0; nt < 4; nt++)
        acc[mt][nt] = __builtin_amdgcn_mfma_f32_16x16x32_bf16(
            af[mt], bfr[nt], acc[mt][nt], 0, 0, 0);
  }
}

// ---------------------------------------------------------------------------
// k_trans: x NCHW fp32 -> xT NHWC bf16 + fused GN1 stats (v2, 256B rows).
// ---------------------------------------------------------------------------
__global__ __launch_bounds__(256) void k_trans(const float* __restrict__ x,
                                               __bf16* __restrict__ xT,
                                               float* __restrict__ stats1)
{
  __shared__ __bf16 tile[64 * 136];
  __shared__ float red[8];
  const int t = threadIdx.x;
  const int pb = blockIdx.x * 64, cb = blockIdx.y * 128, b = blockIdx.z;
  const float* xb = x + (size_t)b * NPB;
  const int p = t & 63, cq = t >> 6;
  float s = 0.f, s2 = 0.f;
#pragma unroll
  for (int h = 0; h < 2; h++){
    float v[16];
#pragma unroll
    for (int u = 0; u < 16; u++){
      int c = cq * 32 + h * 16 + u;
      v[u] = xb[(size_t)(cb + c) * HW + pb + p];
    }
#pragma unroll
    for (int g = 0; g < 4; g++){
      bf4_t pk;
#pragma unroll
      for (int j = 0; j < 4; j++){
        float vv = v[g * 4 + j];
        s += vv; s2 += vv * vv;
        pk.v[j] = (__bf16)vv;
      }
      *(bf4_t*)&tile[p * 136 + cq * 32 + h * 16 + g * 4] = pk;
    }
  }
  __syncthreads();
  __bf16* xTb = xT + (size_t)b * NPB;
#pragma unroll
  for (int si = 0; si < 4; si++){
    int pp = si * 16 + (t >> 4);
    int c0 = (t & 15) * 8;
    *(bf8_t*)(xTb + (size_t)(pb + pp) * CC + cb + c0) =
        *(bf8_t*)&tile[pp * 136 + c0];
  }
  for (int off = 32; off; off >>= 1){
    s  += __shfl_down(s,  off);
    s2 += __shfl_down(s2, off);
  }
  const int wave = t >> 6, lane = t & 63;
  if (lane == 0){ red[wave] = s; red[4 + wave] = s2; }
  __syncthreads();
  if (t == 0){
    atomicAdd(stats1 + b * 2,     red[0] + red[1] + red[2] + red[3]);
    atomicAdd(stats1 + b * 2 + 1, red[4] + red[5] + red[6] + red[7]);
  }
}

// ---------------------------------------------------------------------------
// k_prep: weight folding, one block per output row.
// ---------------------------------------------------------------------------
__global__ __launch_bounds__(256) void k_prep(
    const float* __restrict__ gn1w, const float* __restrict__ gn1b,
    const float* __restrict__ w1,   const float* __restrict__ b1,
    const float* __restrict__ gn2w, const float* __restrict__ gn2b,
    const float* __restrict__ w4,
    const float* __restrict__ w5,   const float* __restrict__ b5,
    const float* __restrict__ wg2,  const float* __restrict__ bg2,
    const float* __restrict__ stats1,
    __bf16* __restrict__ Wc1, float* __restrict__ db1,
    __bf16* __restrict__ W4c, float* __restrict__ S1, float* __restrict__ S2,
    __bf16* __restrict__ W5e, float* __restrict__ b5eff)
{
  __shared__ float redA[4], redB[4];
  const int c = threadIdx.x;
  const int which = blockIdx.x >> 8, o = blockIdx.x & 255;
  float a = 0.f, g = 0.f;
  if (which == 0){
    float w = w1[o * CC + c];
    Wc1[o * CC + c] = (__bf16)(w * gn1w[c]);
    a = w * gn1b[c];
    g = w * gn1w[c];
  } else if (which == 1){
    float w = w4[o * CC + c];
    W4c[o * CC + c] = (__bf16)(w * gn2w[c]);
    a = w * gn2b[c];
    g = w * gn2w[c];
  } else {
    int gr = c >> 2, j = c & 3, base = c & ~3;
    float acc = 0.f;
#pragma unroll
    for (int i = 0; i < 4; i++)
      acc += w5[o * CC + base + i] * wg2[gr * 16 + i * 4 + j];
    W5e[o * CC + c] = (__bf16)acc;
    a = w5[o * CC + c] * bg2[c];
  }
  for (int off = 32; off; off >>= 1){
    a += __shfl_down(a, off);
    g += __shfl_down(g, off);
  }
  const int wave = c >> 6, lane = c & 63;
  if (lane == 0){ redA[wave] = a; redB[wave] = g; }
  __syncthreads();
  if (c == 0){
    float A = redA[0] + redA[1] + redA[2] + redA[3];
    float G = redB[0] + redB[1] + redB[2] + redB[3];
    if (which == 0){
      for (int b = 0; b < 8; b++){
        float ss = stats1[b * 2], sq = stats1[b * 2 + 1];
        float m = ss * (1.f / (float)NPB);
        float r = rsqrtf(sq * (1.f / (float)NPB) - m * m + 1e-5f);
        db1[b * CC + o] = b1[o] + A - m * r * G;
      }
    } else if (which == 1){
      S1[o] = A; S2[o] = G;
    } else {
      b5eff[o] = b5[o] + A;
    }
  }
}

// ---------------------------------------------------------------------------
// k_gemm1: y = bf16( r1_b * (Wc1 @ xT) + db1[b][o] )
// ---------------------------------------------------------------------------
__global__ __launch_bounds__(256) void k_gemm1(
    const __bf16* __restrict__ Wc1, const __bf16* __restrict__ xT,
    const float* __restrict__ db1, const float* __restrict__ stats1,
    __bf16* __restrict__ y)
{
  __shared__ char smem[16384];
  const int pb = blockIdx.x * 128, ob = blockIdx.y * 128, b = blockIdx.z;
  f32x4 acc[4][4];
#pragma unroll
  for (int i = 0; i < 4; i++)
#pragma unroll
    for (int j = 0; j < 4; j++) acc[i][j] = (f32x4){0.f, 0.f, 0.f, 0.f};
  gemm_core(Wc1 + (size_t)ob * CC, xT + ((size_t)b * HW + pb) * CC, smem, acc);

  const int t = threadIdx.x, wave = t >> 6, lane = t & 63;
  const int col = lane & 15, q = lane >> 4;
  const int osub = (wave & 1) * 64, psub = (wave >> 1) * 64;
  float ss = stats1[b * 2], sq = stats1[b * 2 + 1];
  float m  = ss * (1.f / (float)NPB);
  float r1 = rsqrtf(sq * (1.f / (float)NPB) - m * m + 1e-5f);
#pragma unroll
  for (int mt = 0; mt < 4; mt++){
    int o0 = ob + osub + mt * 16 + q * 4;
    f32x4 d = *(const f32x4*)(db1 + b * CC + o0);
#pragma unroll
    for (int nt = 0; nt < 4; nt++){
      int p = pb + psub + nt * 16 + col;
      bf4_t pk;
#pragma unroll
      for (int r = 0; r < 4; r++) pk.v[r] = (__bf16)(r1 * acc[mt][nt][r] + d[r]);
      *(bf4_t*)(y + ((size_t)b * HW + p) * CC + o0) = pk;
    }
  }
}

// ---------------------------------------------------------------------------
// k_dw v2: u = gelu²(dw3x3(y)+b2), pool partial per block.
// Weights register-resident: thread's 8 channels own w2[c8*9 .. c8*9+71]
// (72 consecutive floats, 18x float4).  32 pixels/block (4 iters of 8),
// pool partials in regs -> one pitch-33 conflict-free LDS reduction ->
// one atomic per thread.  grid (512, 8), block 256 (ci = t&31, py = t>>5).
// ---------------------------------------------------------------------------
__global__ __launch_bounds__(256) void k_dw(
    const __bf16* __restrict__ y, const float* __restrict__ w2,
    const float* __restrict__ b2, __bf16* __restrict__ u,
    float* __restrict__ pool)
{
  __shared__ float pl[64 * 33];   // [(j*8+py)][ci] pitch 33 -> conflict-free
  const int t = threadIdx.x;
  const int ci = t & 31, py = t >> 5;
  const int c8 = ci * 8;
  const int b = blockIdx.y;

  // 72 consecutive weights for this thread's 8 channels -> registers
  float buf[72];
  {
    const f32x4* wp = (const f32x4*)(w2 + c8 * 9);
#pragma unroll
    for (int i = 0; i < 18; i++){
      f32x4 v = wp[i];
      buf[i*4+0] = v[0]; buf[i*4+1] = v[1]; buf[i*4+2] = v[2]; buf[i*4+3] = v[3];
    }
  }
  float b2r[8];
  {
    f32x4 v0 = *(const f32x4*)(b2 + c8);
    f32x4 v1 = *(const f32x4*)(b2 + c8 + 4);
#pragma unroll
    for (int r = 0; r < 4; r++){ b2r[r] = v0[r]; b2r[4+r] = v1[r]; }
  }

  const __bf16* yb = y + (size_t)b * NPB;
  const int p0 = blockIdx.x * 32;
  float preg[8];
#pragma unroll
  for (int j = 0; j < 8; j++) preg[j] = 0.f;

#pragma unroll
  for (int it = 0; it < 4; it++){
    const int p = p0 + it * 8 + py;
    const int h = p >> 7, w = p & 127;
    float acc[8];
#pragma unroll
    for (int j = 0; j < 8; j++) acc[j] = b2r[j];
#pragma unroll
    for (int ky = -1; ky <= 1; ky++){
      int hh = h + ky;
      if ((unsigned)hh >= 128u) continue;
#pragma unroll
      for (int kx = -1; kx <= 1; kx++){
        int ww = w + kx;
        if ((unsigned)ww >= 128u) continue;
        bf16x8 v = *(const bf16x8*)(yb + (size_t)(hh * 128 + ww) * CC + c8);
        const int tap = (ky + 1) * 3 + (kx + 1);
#pragma unroll
        for (int j = 0; j < 8; j++)
          acc[j] += buf[j * 9 + tap] * (float)v[j];
      }
    }
    bf8_t out;
#pragma unroll
    for (int j = 0; j < 8; j++){
      float g = gelu1(gelu1(acc[j]));
      out.v[j] = (__bf16)g;
      preg[j] += g;
    }
    *(bf8_t*)(u + ((size_t)b * HW + p) * CC + c8) = out;
  }
#pragma unroll
  for (int j = 0; j < 8; j++) pl[(j * 8 + py) * 33 + ci] = preg[j];
  __syncthreads();
  // thread t == channel c: ci = c>>3, j = c&7
  float s = 0.f;
#pragma unroll
  for (int pp = 0; pp < 8; pp++) s += pl[((t & 7) * 8 + pp) * 33 + (t >> 3)];
  atomicAdd(pool + b * CC + t, s);
}

// ---------------------------------------------------------------------------
// k_att (small): pooled -> px1 -> att; writes attB[b][256] and b3eff.
// ---------------------------------------------------------------------------
__global__ __launch_bounds__(256) void k_att(
    const float* __restrict__ pool, const float* __restrict__ wg1,
    const float* __restrict__ bg1,  const float* __restrict__ wsca,
    const float* __restrict__ bsca, const float* __restrict__ w3,
    const float* __restrict__ b3,
    float* __restrict__ attB, float* __restrict__ b3eff)
{
  __shared__ float wg1s[1024];
  __shared__ float px1[256];
  __shared__ float attL[256];
  const int t = threadIdx.x, b = blockIdx.x;
  for (int i = t; i < 1024; i += 256) wg1s[i] = wg1[i];
  __syncthreads();
  {
    int g = t >> 2, oo = t & 3;
    float a = bg1[t];
#pragma unroll
    for (int j = 0; j < 4; j++)
      a += wg1s[g * 16 + oo * 4 + j] * (pool[b * CC + g * 4 + j] * (1.f / (float)HW));
    px1[t] = a;
  }
  __syncthreads();
  {
    float a = bsca[t];
    const float* wr = wsca + t * CC;
    for (int c = 0; c < CC; c++) a += wr[c] * px1[c];
    attL[t] = a;
    attB[b * CC + t] = a;
  }
  __syncthreads();
  {
    float bb = b3[t];
    const float* wr = w3 + t * CC;
    for (int c = 0; c < CC; c++) bb += wr[c] * attL[c] * bg1[c];
    b3eff[b * CC + t] = bb;
  }
}

// ---------------------------------------------------------------------------
// k_attW: W3b[b] = w3 @ diag(att) @ blockdiag(wg1), parallel fold.
// ---------------------------------------------------------------------------
__global__ __launch_bounds__(256) void k_attW(
    const float* __restrict__ attB, const float* __restrict__ w3,
    const float* __restrict__ wg1, __bf16* __restrict__ W3b)
{
  __shared__ float w3s[4096];
  __shared__ float wg1s[1024];
  __shared__ float attS[256];
  const int t = threadIdx.x;
  const int og = blockIdx.x, b = blockIdx.y;
  const int o0 = og * 16;
  for (int i = t; i < 4096; i += 256) w3s[i] = w3[o0 * 256 + i];
  for (int i = t; i < 1024; i += 256) wg1s[i] = wg1[i];
  attS[t] = attB[b * 256 + t];
  __syncthreads();
  const int ol = t >> 4, ci = t & 15;
  __bf16* out = W3b + (size_t)b * 65536 + (size_t)(o0 + ol) * 256;
#pragma unroll
  for (int cc = 0; cc < 16; cc++){
    int c = cc * 16 + ci;
    int g = c >> 2, j = c & 3, base = c & ~3;
    float a = 0.f;
#pragma unroll
    for (int i = 0; i < 4; i++)
      a += w3s[ol * 256 + base + i] * attS[base + i] * wg1s[g * 16 + i * 4 + j];
    out[c] = (__bf16)a;
  }
}

// ---------------------------------------------------------------------------
// k_gemm3: x1res = bf16( (W3b@u + b3eff)*beta + x ), fused GN2 stats.
// ---------------------------------------------------------------------------
__global__ __launch_bounds__(256) void k_gemm3(
    const __bf16* __restrict__ W3b, const __bf16* __restrict__ u,
    const float* __restrict__ b3eff, const float* __restrict__ beta,
    const __bf16* __restrict__ xT,
    __bf16* __restrict__ x1r, float* __restrict__ stats2)
{
  __shared__ char smem[16384];
  const int pb = blockIdx.x * 128, ob = blockIdx.y * 128, b = blockIdx.z;
  f32x4 acc[4][4];
#pragma unroll
  for (int i = 0; i < 4; i++)
#pragma unroll
    for (int j = 0; j < 4; j++) acc[i][j] = (f32x4){0.f, 0.f, 0.f, 0.f};
  gemm_core(W3b + (size_t)b * 65536 + (size_t)ob * CC,
            u + ((size_t)b * HW + pb) * CC, smem, acc);

  const int t = threadIdx.x, wave = t >> 6, lane = t & 63;
  const int col = lane & 15, q = lane >> 4;
  const int osub = (wave & 1) * 64, psub = (wave >> 1) * 64;
  float ls = 0.f, lsq = 0.f;
#pragma unroll
  for (int mt = 0; mt < 4; mt++){
    int o0 = ob + osub + mt * 16 + q * 4;
    f32x4 be = *(const f32x4*)(b3eff + b * CC + o0);
    f32x4 bt = *(const f32x4*)(beta + o0);
#pragma unroll
    for (int nt = 0; nt < 4; nt++){
      int p = pb + psub + nt * 16 + col;
      bf4_t xr = *(const bf4_t*)(xT + ((size_t)b * HW + p) * CC + o0);
      bf4_t pk;
#pragma unroll
      for (int r = 0; r < 4; r++){
        float v = acc[mt][nt][r] + be[r];
        v = v * bt[r] + (float)xr.v[r];
        pk.v[r] = (__bf16)v;
        ls += v; lsq += v * v;
      }
      *(bf4_t*)(x1r + ((size_t)b * HW + p) * CC + o0) = pk;
    }
  }
  for (int off = 32; off; off >>= 1){
    ls  += __shfl_down(ls,  off);
    lsq += __shfl_down(lsq, off);
  }
  __syncthreads();
  float* red = (float*)smem;
  if (lane == 0){ red[wave] = ls; red[4 + wave] = lsq; }
  __syncthreads();
  if (t == 0){
    atomicAdd(stats2 + b * 2,     red[0] + red[1] + red[2] + red[3]);
    atomicAdd(stats2 + b * 2 + 1, red[4] + red[5] + red[6] + red[7]);
  }
}

// ---------------------------------------------------------------------------
// k_gemm4: g = bf16( gelu²( r2_b*(W4c@x1r) + (b4 + S1 - m2*r2*S2) ) )
// ---------------------------------------------------------------------------
__global__ __launch_bounds__(256) void k_gemm4(
    const __bf16* __restrict__ W4c, const __bf16* __restrict__ x1r,
    const float* __restrict__ b4, const float* __restrict__ S1,
    const float* __restrict__ S2, const float* __restrict__ stats2,
    __bf16* __restrict__ g)
{
  __shared__ char smem[16384];
  const int pb = blockIdx.x * 128, ob = blockIdx.y * 128, b = blockIdx.z;
  f32x4 acc[4][4];
#pragma unroll
  for (int i = 0; i < 4; i++)
#pragma unroll
    for (int j = 0; j < 4; j++) acc[i][j] = (f32x4){0.f, 0.f, 0.f, 0.f};
  gemm_core(W4c + (size_t)ob * CC, x1r + ((size_t)b * HW + pb) * CC, smem, acc);

  const int t = threadIdx.x, wave = t >> 6, lane = t & 63;
  const int col = lane & 15, q = lane >> 4;
  const int osub = (wave & 1) * 64, psub = (wave >> 1) * 64;
  float ss = stats2[b * 2], sq = stats2[b * 2 + 1];
  float m2 = ss * (1.f / (float)NPB);
  float r2 = rsqrtf(sq * (1.f / (float)NPB) - m2 * m2 + 1e-5f);
#pragma unroll
  for (int mt = 0; mt < 4; mt++){
    int o0 = ob + osub + mt * 16 + q * 4;
    f32x4 b4v = *(const f32x4*)(b4 + o0);
    f32x4 s1v = *(const f32x4*)(S1 + o0);
    f32x4 s2v = *(const f32x4*)(S2 + o0);
    float db[4];
#pragma unroll
    for (int r = 0; r < 4; r++) db[r] = b4v[r] + s1v[r] - m2 * r2 * s2v[r];
#pragma unroll
    for (int nt = 0; nt < 4; nt++){
      int p = pb + psub + nt * 16 + col;
      bf4_t pk;
#pragma unroll
      for (int r = 0; r < 4; r++){
        float v = r2 * acc[mt][nt][r] + db[r];
        pk.v[r] = (__bf16)gelu1(gelu1(v));
      }
      *(bf4_t*)(g + ((size_t)b * HW + p) * CC + o0) = pk;
    }
  }
}

// ---------------------------------------------------------------------------
// k_gemm5: out(NCHW fp32) = (W5e@g + b5eff)*gamma + x1res
// ---------------------------------------------------------------------------
__global__ __launch_bounds__(256) void k_gemm5(
    const __bf16* __restrict__ W5e, const __bf16* __restrict__ g,
    const float* __restrict__ b5eff, const float* __restrict__ gamma,
    const __bf16* __restrict__ x1r, float* __restrict__ out)
{
  __shared__ char smem[16384];
  const int pb = blockIdx.x * 128, ob = blockIdx.y * 128, b = blockIdx.z;
  f32x4 acc[4][4];
#pragma unroll
  for (int i = 0; i < 4; i++)
#pragma unroll
    for (int j = 0; j < 4; j++) acc[i][j] = (f32x4){0.f, 0.f, 0.f, 0.f};
  gemm_core(W5e + (size_t)ob * CC, g + ((size_t)b * HW + pb) * CC, smem, acc);

  const int t = threadIdx.x, wave = t >> 6, lane = t & 63;
  const int col = lane & 15, q = lane >> 4;
  const int osub = (wave & 1) * 64, psub = (wave >> 1) * 64;
#pragma unroll
  for (int mt = 0; mt < 4; mt++){
    int o0 = ob + osub + mt * 16 + q * 4;
    f32x4 b5v = *(const f32x4*)(b5eff + o0);
    f32x4 gmv = *(const f32x4*)(gamma + o0);
#pragma unroll
    for (int nt = 0; nt < 4; nt++){
      int p = pb + psub + nt * 16 + col;
      bf4_t xr = *(const bf4_t*)(x1r + ((size_t)b * HW + p) * CC + o0);
#pragma unroll
      for (int r = 0; r < 4; r++){
        float v = acc[mt][nt][r] + b5v[r];
        v = v * gmv[r] + (float)xr.v[r];
        out[(size_t)(b * CC + o0 + r) * HW + p] = v;
      }
    }
  }
}

// ---------------------------------------------------------------------------
extern "C" void kernel_launch(void* const* d_in, const int* in_sizes, int n_in,
                              void* d_out, int out_size, void* d_ws, size_t ws_size,
                              hipStream_t stream)
{
  (void)in_sizes; (void)n_in; (void)out_size; (void)ws_size;
  const float* x     = (const float*)d_in[0];
  const float* gn1w  = (const float*)d_in[1];
  const float* gn1b  = (const float*)d_in[2];
  const float* w1    = (const float*)d_in[3];
  const float* b1    = (const float*)d_in[4];
  const float* w2    = (const float*)d_in[5];
  const float* b2    = (const float*)d_in[6];
  const float* wg1   = (const float*)d_in[7];
  const float* bg1   = (const float*)d_in[8];
  const float* wsca  = (const float*)d_in[9];
  const float* bsca  = (const float*)d_in[10];
  const float* w3    = (const float*)d_in[11];
  const float* b3    = (const float*)d_in[12];
  const float* gn2w  = (const float*)d_in[13];
  const float* gn2b  = (const float*)d_in[14];
  const float* w4    = (const float*)d_in[15];
  const float* b4    = (const float*)d_in[16];
  const float* wg2   = (const float*)d_in[17];
  const float* bg2   = (const float*)d_in[18];
  const float* w5    = (const float*)d_in[19];
  const float* b5    = (const float*)d_in[20];
  const float* beta  = (const float*)d_in[21];
  const float* gamma = (const float*)d_in[22];

  char* ws = (char*)d_ws;
  __bf16* xT  = (__bf16*)(ws + 0);            // 64 MB  NHWC bf16 of x
  __bf16* y   = (__bf16*)(ws + 67108864);     // 64 MB  conv1 out; reused as g
  __bf16* u   = (__bf16*)(ws + 134217728);    // 64 MB  gelu²(dwconv) out
  __bf16* x1r = (__bf16*)(ws + 201326592);    // 64 MB  x1 residual carrier
  char*   sm  = ws + 268435456;
  float* stats1 = (float*)(sm);            // 16 f32
  float* stats2 = (float*)(sm + 64);       // 16 f32
  float* pool   = (float*)(sm + 128);      // 2048 f32 (ends 8320)
  float* db1    = (float*)(sm + 8320);     // 2048 f32
  float* S1     = (float*)(sm + 16512);    // 256 f32
  float* S2     = (float*)(sm + 17536);    // 256 f32
  float* b3eff  = (float*)(sm + 18560);    // 2048 f32
  float* b5eff  = (float*)(sm + 26752);    // 256 f32
  float* attB   = (float*)(sm + 27776);    // 2048 f32
  __bf16* Wc1   = (__bf16*)(sm + 36864);   // 128 KB
  __bf16* W4c   = (__bf16*)(sm + 167936);  // 128 KB
  __bf16* W5e   = (__bf16*)(sm + 299008);  // 128 KB
  __bf16* W3b   = (__bf16*)(sm + 430080);  // 1 MB (8 batches)

  hipMemsetAsync(sm, 0, 8320, stream);  // zero stats1, stats2, pool

  k_trans<<<dim3(256, 2, 8), 256, 0, stream>>>(x, xT, stats1);
  k_prep <<<768, 256, 0, stream>>>(gn1w, gn1b, w1, b1, gn2w, gn2b, w4,
                                   w5, b5, wg2, bg2, stats1,
                                   Wc1, db1, W4c, S1, S2, W5e, b5eff);
  k_gemm1<<<dim3(128, 2, 8), 256, 0, stream>>>(Wc1, xT, db1, stats1, y);
  k_dw   <<<dim3(512, 8), 256, 0, stream>>>(y, w2, b2, u, pool);
  k_att  <<<8, 256, 0, stream>>>(pool, wg1, bg1, wsca, bsca, w3, b3, attB, b3eff);
  k_attW <<<dim3(16, 8), 256, 0, stream>>>(attB, w3, wg1, W3b);
  k_gemm3<<<dim3(128, 2, 8), 256, 0, stream>>>(W3b, u, b3eff, beta, xT, x1r, stats2);
  k_gemm4<<<dim3(128, 2, 8), 256, 0, stream>>>(W4c, x1r, b4, S1, S2, stats2, y);
  k_gemm5<<<dim3(128, 2, 8), 256, 0, stream>>>(W5e, y, b5eff, gamma, x1r,
                                               (float*)d_out);
}